// Round 7
// baseline (9307.483 us; speedup 1.0000x reference)
//
#include <hip/hip_runtime.h>
#include <math.h>

#define NTOK   8192   // B*S
#define DMODEL 2048
#define DFF    8192
#define NEXP   8
#define DR     1024   // D/2
#define EPH    4      // experts per staging phase (wb holds EPH experts)

typedef __attribute__((ext_vector_type(4))) float f32x4;
typedef __attribute__((ext_vector_type(8))) short s16x8;

__device__ __forceinline__ float gelu_f(float x){
  return 0.5f * x * (1.0f + erff(x * 0.70710678118654752440f));
}
__device__ __forceinline__ unsigned short f2bf(float f){
  unsigned u = __builtin_bit_cast(unsigned, f);
  u += 0x7FFFu + ((u >> 16) & 1u);        // RNE
  return (unsigned short)(u >> 16);
}
__device__ __forceinline__ void gload_lds16(const void* g, void* l){
  __builtin_amdgcn_global_load_lds(
      (const __attribute__((address_space(1))) unsigned int*)g,
      (__attribute__((address_space(3))) unsigned int*)l, 16, 0, 0);
}

// ---------------- init / casts ----------------
__global__ void k_init(int* cnt, float* usage){
  int i = threadIdx.x;
  if (i < 8){ cnt[i] = 0; usage[i] = 0.f; }
}

__global__ void k_cast_x(const float* __restrict__ x, unsigned short* __restrict__ xb){
  int i = blockIdx.x * blockDim.x + threadIdx.x;
  int stride = gridDim.x * blockDim.x;
  const int n8 = NTOK * DMODEL / 8;
  for (; i < n8; i += stride){
    const float4* p = (const float4*)(x + (size_t)i * 8);
    float4 a = p[0], b = p[1];
    uint4 o;
    o.x = (unsigned)f2bf(a.x) | ((unsigned)f2bf(a.y) << 16);
    o.y = (unsigned)f2bf(a.z) | ((unsigned)f2bf(a.w) << 16);
    o.z = (unsigned)f2bf(b.x) | ((unsigned)f2bf(b.y) << 16);
    o.w = (unsigned)f2bf(b.z) | ((unsigned)f2bf(b.w) << 16);
    *(uint4*)(xb + (size_t)i * 8) = o;
  }
}

// transpose + cast fp32[R][C] -> bf16[C][R]; input expert = blockIdx.z + ebase,
// output slot = blockIdx.z (wb holds EPH experts per phase)
__global__ void k_tcast(const float* __restrict__ in, unsigned short* __restrict__ out,
                        int R, int C, int ebase){
  __shared__ float tile[32][33];
  const float* ine = in + (size_t)(blockIdx.z + ebase) * R * C;
  unsigned short* oute = out + (size_t)blockIdx.z * R * C;
  int c0 = blockIdx.x * 32, r0 = blockIdx.y * 32;
  int tx = threadIdx.x & 31, ty = threadIdx.x >> 5;   // 256 thr: ty 0..7
  #pragma unroll
  for (int i = 0; i < 32; i += 8)
    tile[ty + i][tx] = ine[(size_t)(r0 + ty + i) * C + (c0 + tx)];
  __syncthreads();
  #pragma unroll
  for (int i = 0; i < 32; i += 8)
    oute[(size_t)(c0 + ty + i) * R + (r0 + tx)] = f2bf(tile[tx][ty + i]);
}

// ---------------- router L1: fp32 SIMT GEMM + bias + gelu ----------------
// G[8192][1024] = gelu(x[8192][2048] @ Wr1[2048][1024] + br1)
__global__ __launch_bounds__(256)
void k_router_gemm(const float* __restrict__ X, const float* __restrict__ W,
                   const float* __restrict__ b1r, float* __restrict__ G)
{
  __shared__ float As[8][128];
  __shared__ float Bs[8][132];
  const int m0 = blockIdx.y * 128, n0 = blockIdx.x * 128;
  const int tid = threadIdx.x;
  const int tm = tid >> 4, tn = tid & 15;
  const int am = tid >> 1, ak = (tid & 1) << 2;
  const int bk = tid >> 5, bn = (tid & 31) << 2;
  float c[8][8];
  #pragma unroll
  for (int i = 0; i < 8; ++i)
    #pragma unroll
    for (int j = 0; j < 8; ++j) c[i][j] = 0.f;

  for (int k0 = 0; k0 < DMODEL; k0 += 8){
    float4 a = *(const float4*)(X + (size_t)(m0 + am) * DMODEL + (k0 + ak));
    float4 b = *(const float4*)(W + (size_t)(k0 + bk) * DR + (n0 + bn));
    __syncthreads();
    As[ak + 0][am] = a.x; As[ak + 1][am] = a.y; As[ak + 2][am] = a.z; As[ak + 3][am] = a.w;
    *(float4*)&Bs[bk][bn] = b;
    __syncthreads();
    #pragma unroll
    for (int k = 0; k < 8; ++k){
      float av[8], bv[8];
      #pragma unroll
      for (int i = 0; i < 8; ++i){ av[i] = As[k][tm * 8 + i]; bv[i] = Bs[k][tn * 8 + i]; }
      #pragma unroll
      for (int i = 0; i < 8; ++i)
        #pragma unroll
        for (int j = 0; j < 8; ++j)
          c[i][j] = fmaf(av[i], bv[j], c[i][j]);
    }
  }
  #pragma unroll
  for (int i = 0; i < 8; ++i){
    int row = m0 + tm * 8 + i;
    #pragma unroll
    for (int j = 0; j < 8; ++j){
      int col = n0 + tn * 8 + j;
      G[(size_t)row * DR + col] = gelu_f(c[i][j] + b1r[col]);
    }
  }
}

// ---------------- router L2 + top-k + dispatch lists ----------------
__global__ __launch_bounds__(256)
void k_router2(const float* __restrict__ G, const float* __restrict__ Wr2, const float* __restrict__ br2,
               int* __restrict__ cnt, int* __restrict__ tokA, float* __restrict__ pwA, int* __restrict__ pkA,
               float* __restrict__ usage)
{
  const int t = blockIdx.x * 4 + (threadIdx.x >> 6);   // wave per token
  const int lane = threadIdx.x & 63;
  const float* g = G + (size_t)t * DR;
  float acc[8];
  #pragma unroll
  for (int e = 0; e < 8; ++e) acc[e] = 0.f;
  for (int i = lane; i < DR; i += 64){
    float gv = g[i];
    float4 wa = *(const float4*)(Wr2 + (size_t)i * 8);
    float4 wb = *(const float4*)(Wr2 + (size_t)i * 8 + 4);
    acc[0] = fmaf(gv, wa.x, acc[0]); acc[1] = fmaf(gv, wa.y, acc[1]);
    acc[2] = fmaf(gv, wa.z, acc[2]); acc[3] = fmaf(gv, wa.w, acc[3]);
    acc[4] = fmaf(gv, wb.x, acc[4]); acc[5] = fmaf(gv, wb.y, acc[5]);
    acc[6] = fmaf(gv, wb.z, acc[6]); acc[7] = fmaf(gv, wb.w, acc[7]);
  }
  #pragma unroll
  for (int d = 1; d < 64; d <<= 1){
    #pragma unroll
    for (int e = 0; e < 8; ++e) acc[e] += __shfl_xor(acc[e], d, 64);
  }
  if (lane == 0){
    float l[8]; float mx = -3.4e38f;
    #pragma unroll
    for (int e = 0; e < 8; ++e){ l[e] = acc[e] + br2[e]; mx = fmaxf(mx, l[e]); }
    float p[8], su = 0.f;
    #pragma unroll
    for (int e = 0; e < 8; ++e){ p[e] = expf(l[e] - mx); su += p[e]; }
    float inv = 1.0f / (su * (float)NTOK);
    #pragma unroll
    for (int e = 0; e < 8; ++e) atomicAdd(&usage[e], p[e] * inv);
    int i0 = 0;
    #pragma unroll
    for (int e = 1; e < 8; ++e) if (l[e] > l[i0]) i0 = e;
    int i1 = (i0 == 0) ? 1 : 0;
    #pragma unroll
    for (int e = 0; e < 8; ++e) if (e != i0 && l[e] > l[i1]) i1 = e;
    float w0 = 1.0f / (1.0f + expf(l[i1] - l[i0]));
    float w1 = 1.0f - w0;
    int p0 = atomicAdd(&cnt[i0], 1);
    tokA[i0 * NTOK + p0] = t; pwA[i0 * NTOK + p0] = w0; pkA[i0 * NTOK + p0] = 0;
    int p1 = atomicAdd(&cnt[i1], 1);
    tokA[i1 * NTOK + p1] = t; pwA[i1 * NTOK + p1] = w1; pkA[i1 * NTOK + p1] = 1;
  }
}

__global__ void k_scan(const int* __restrict__ cnt, int* __restrict__ off){
  if (threadIdx.x == 0 && blockIdx.x == 0){
    int a = 0;
    for (int e = 0; e < 8; ++e){ off[e] = a; a += cnt[e]; }
    off[8] = a;
  }
}

// ---------------- expert GEMMs (bf16 MFMA, 128x128 tile, BK=64) ----------------
// MODE 0: H[slot][F] = gelu( gather(xb)[slot][D] @ w1b[e]^T + b1[e] )   (w1b: [F][D])
// MODE 1: out/ob1[tok][D] = w * ( H[slot][F] @ w2b[e]^T + b2[e] )       (w2b: [D][F])
// ebase: global expert id = blockIdx.z + ebase; wb panel slot = blockIdx.z.
template<int MODE>
__global__ __launch_bounds__(256)
void k_moe_gemm(const unsigned short* __restrict__ Ag,
                const unsigned short* __restrict__ Bg,
                const float* __restrict__ bias,
                unsigned short* __restrict__ Hout,
                float* __restrict__ ob0, float* __restrict__ ob1,
                const int* __restrict__ cntArr, const int* __restrict__ offArr,
                const int* __restrict__ tokArr, const float* __restrict__ pwArr,
                const int* __restrict__ pkArr, int ebase)
{
  constexpr int KTOT = (MODE == 0) ? DMODEL : DFF;
  constexpr int NTOT = (MODE == 0) ? DFF : DMODEL;
  // T1 XCD-aware swizzle (bijective: nwg % 8 == 0). Same-XCD blocks become a
  // contiguous raster chunk -> shared A-panel stays in that XCD's L2.
  constexpr int GX = NTOT / 128;          // 64 (MODE 0) or 16 (MODE 1)
  constexpr int GY = NTOK / 128;          // 64
  constexpr int NWG = GX * GY;            // 4096 / 1024
  constexpr int QQ = NWG / 8;
  const int flat = blockIdx.y * GX + blockIdx.x;
  const int swz  = (flat & 7) * QQ + (flat >> 3);
  const int bx = swz % GX, by = swz / GX;

  const int el = blockIdx.z;              // local wb slot
  const int e  = el + ebase;              // global expert id
  const int cnt = cntArr[e];
  const int m0 = by * 128;
  if (m0 >= cnt) return;
  const int n0 = bx * 128;
  const int eoff = offArr[e];

  __shared__ unsigned short As[128 * 64];
  __shared__ unsigned short Bs[128 * 64];

  const int tid = threadIdx.x;
  const int lane = tid & 63;
  const int wave = tid >> 6;
  const int wr = wave >> 1, wc = wave & 1;

  const unsigned short* Bbase = Bg + (size_t)el * ((size_t)NTOT * KTOT);

  // staging geometry: 16B chunk c -> LDS row r = c/8, col (c%8)*8; source col
  // pre-swizzled (inverse of read-side XOR) so linear global_load_lds + swizzled
  // ds_read are consistent (rule #21).
  size_t arow[4], brow[4]; int kpr[4];
  #pragma unroll
  for (int p = 0; p < 4; ++p){
    int c = p * 256 + tid;
    int r = c >> 3;
    int kc = (c & 7) << 3;
    kpr[p] = kc ^ ((r & 7) << 3);
    int s = m0 + r;
    int sc = (s < cnt) ? s : (cnt - 1);
    if (MODE == 0){
      int t = tokArr[e * NTOK + sc];
      arow[p] = (size_t)t * KTOT;
    } else {
      arow[p] = (size_t)(eoff + sc) * KTOT;
    }
    brow[p] = (size_t)(n0 + r) * KTOT;
  }

  const f32x4 fzero = {0.f, 0.f, 0.f, 0.f};
  f32x4 acc[4][4];
  #pragma unroll
  for (int m = 0; m < 4; ++m)
    #pragma unroll
    for (int n = 0; n < 4; ++n) acc[m][n] = fzero;

  for (int k0 = 0; k0 < KTOT; k0 += 64){
    #pragma unroll
    for (int p = 0; p < 4; ++p){
      gload_lds16(Ag + (arow[p] + (size_t)(k0 + kpr[p])), (char*)As + ((p * 256 + tid) * 16));
      gload_lds16(Bbase + (brow[p] + (size_t)(k0 + kpr[p])), (char*)Bs + ((p * 256 + tid) * 16));
    }
    __syncthreads();
    #pragma unroll
    for (int kk = 0; kk < 2; ++kk){
      s16x8 av[4], bv[4];
      #pragma unroll
      for (int m = 0; m < 4; ++m){
        int r = wr * 64 + m * 16 + (lane & 15);
        int off = r * 128 + ((kk * 32 + (lane >> 4) * 8) << 1);
        off ^= (r & 7) << 4;
        av[m] = *(const s16x8*)((const char*)As + off);
      }
      #pragma unroll
      for (int n = 0; n < 4; ++n){
        int r = wc * 64 + n * 16 + (lane & 15);
        int off = r * 128 + ((kk * 32 + (lane >> 4) * 8) << 1);
        off ^= (r & 7) << 4;
        bv[n] = *(const s16x8*)((const char*)Bs + off);
      }
      #pragma unroll
      for (int m = 0; m < 4; ++m)
        #pragma unroll
        for (int n = 0; n < 4; ++n)
          acc[m][n] = __builtin_amdgcn_mfma_f32_16x16x32_bf16(av[m], bv[n], acc[m][n], 0, 0, 0);
    }
    __syncthreads();
  }

  // epilogue; C/D layout: col = lane&15, row = (lane>>4)*4 + j
  #pragma unroll
  for (int m = 0; m < 4; ++m){
    #pragma unroll
    for (int j = 0; j < 4; ++j){
      int rl = wr * 64 + m * 16 + (lane >> 4) * 4 + j;
      int s = m0 + rl;
      if (s >= cnt) continue;
      if (MODE == 0){
        size_t hrow = (size_t)(eoff + s) * DFF;
        #pragma unroll
        for (int n = 0; n < 4; ++n){
          int col = n0 + wc * 64 + n * 16 + (lane & 15);
          float v = acc[m][n][j] + bias[(size_t)e * DFF + col];
          Hout[hrow + col] = f2bf(gelu_f(v));
        }
      } else {
        int   t  = tokArr[e * NTOK + s];
        float wgt = pwArr[e * NTOK + s];
        int   kk = pkArr[e * NTOK + s];
        float* dst = (kk ? ob1 : ob0) + (size_t)t * DMODEL;
        #pragma unroll
        for (int n = 0; n < 4; ++n){
          int col = n0 + wc * 64 + n * 16 + (lane & 15);
          dst[col] = (acc[m][n][j] + bias[(size_t)e * DMODEL + col]) * wgt;
        }
      }
    }
  }
}

// ---------------- combine (in-place: o += b) + lb ----------------
__global__ void k_add_inplace(float* __restrict__ o, const float* __restrict__ b){
  int i = blockIdx.x * blockDim.x + threadIdx.x;
  int stride = gridDim.x * blockDim.x;
  const int n4 = NTOK * DMODEL / 4;
  for (; i < n4; i += stride){
    float4 x = ((const float4*)o)[i], y = ((const float4*)b)[i];
    float4 r; r.x = x.x + y.x; r.y = x.y + y.y; r.z = x.z + y.z; r.w = x.w + y.w;
    ((float4*)o)[i] = r;
  }
}

__global__ void k_lb(const float* __restrict__ usage, float* __restrict__ out){
  if (threadIdx.x == 0 && blockIdx.x == 0){
    float s = 0.f;
    for (int e = 0; e < 8; ++e) s += usage[e];
    float mean = s / 8.f, v = 0.f;
    for (int e = 0; e < 8; ++e){ float d = usage[e] - mean; v += d * d; }
    out[0] = 0.01f * (v / 7.f);   // unbiased var (ddof=1) * LB_W
  }
}

// ---------------- launch ----------------
extern "C" void kernel_launch(void* const* d_in, const int* in_sizes, int n_in,
                              void* d_out, int out_size, void* d_ws, size_t ws_size,
                              hipStream_t stream)
{
  const float* x   = (const float*)d_in[0];
  const float* Wr1 = (const float*)d_in[1];
  const float* br1 = (const float*)d_in[2];
  const float* Wr2 = (const float*)d_in[3];
  const float* br2 = (const float*)d_in[4];
  const float* W1  = (const float*)d_in[5];
  const float* b1  = (const float*)d_in[6];
  const float* W2  = (const float*)d_in[7];
  const float* b2  = (const float*)d_in[8];
  float* out = (float*)d_out;

  char* w = (char*)d_ws;
  size_t o = 0;
  auto alloc = [&](size_t bytes) -> void* {
    void* p = w + o; o += (bytes + 255) & ~(size_t)255; return p;
  };
  // wb holds EPH=4 experts at a time (two staging phases per layer).
  unsigned short* xb  = (unsigned short*)alloc((size_t)NTOK * DMODEL * 2);   //  32 MB
  unsigned short* wb  = (unsigned short*)alloc((size_t)EPH * DMODEL * DFF * 2); // 128 MB
  unsigned short* H   = (unsigned short*)alloc((size_t)2 * NTOK * DFF * 2);  // 256 MB
  float* G    = (float*)alloc((size_t)NTOK * DR * 4);                        //  32 MB
  float* ob1  = (float*)alloc((size_t)NTOK * DMODEL * 4);                    //  64 MB
  int*   tokA = (int*)alloc((size_t)NEXP * NTOK * 4);
  float* pwA  = (float*)alloc((size_t)NEXP * NTOK * 4);
  int*   pkA  = (int*)alloc((size_t)NEXP * NTOK * 4);
  int*   cnt  = (int*)alloc(256);
  int*   offA = (int*)alloc(256);
  float* usage= (float*)alloc(256);
  // high-water ~515 MB

  hipLaunchKernelGGL(k_init, dim3(1), dim3(64), 0, stream, cnt, usage);
  hipLaunchKernelGGL(k_cast_x, dim3(2048), dim3(256), 0, stream, x, xb);
  hipLaunchKernelGGL(k_router_gemm, dim3(DR / 128, NTOK / 128), dim3(256), 0, stream, x, Wr1, br1, G);
  hipLaunchKernelGGL(k_router2, dim3(NTOK / 4), dim3(256), 0, stream, G, Wr2, br2, cnt, tokA, pwA, pkA, usage);
  hipLaunchKernelGGL(k_scan, dim3(1), dim3(1), 0, stream, cnt, offA);
  // layer 1: per 4-expert phase, cast W1^T then GEMM1 (xb @ wb^T -> H)
  for (int eb = 0; eb < NEXP; eb += EPH){
    hipLaunchKernelGGL(k_tcast, dim3(DFF / 32, DMODEL / 32, EPH), dim3(256), 0, stream, W1, wb, DMODEL, DFF, eb);
    hipLaunchKernelGGL((k_moe_gemm<0>), dim3(DFF / 128, NTOK / 128, EPH), dim3(256), 0, stream,
                       xb, wb, b1, H, (float*)nullptr, (float*)nullptr, cnt, offA, tokA, pwA, pkA, eb);
  }
  // layer 2: per 4-expert phase, cast W2^T then GEMM2 (H @ wb^T -> out / ob1)
  for (int eb = 0; eb < NEXP; eb += EPH){
    hipLaunchKernelGGL(k_tcast, dim3(DMODEL / 32, DFF / 32, EPH), dim3(256), 0, stream, W2, wb, DFF, DMODEL, eb);
    hipLaunchKernelGGL((k_moe_gemm<1>), dim3(DMODEL / 128, NTOK / 128, EPH), dim3(256), 0, stream,
                       H, wb, b2, (unsigned short*)nullptr, out, ob1, cnt, offA, tokA, pwA, pkA, eb);
  }
  hipLaunchKernelGGL(k_add_inplace, dim3(4096), dim3(256), 0, stream, out, ob1);
  hipLaunchKernelGGL(k_lb, dim3(1), dim3(1), 0, stream, usage, out + (size_t)NTOK * DMODEL);
}